// Round 12
// baseline (577.875 us; speedup 1.0000x reference)
//
#include <hip/hip_runtime.h>

// Fused 3-layer GCN (GS=7, H=144) + pool + fc, B=65536.  Round 12.
// R11 issue-accounting: VALU 45% (premix at its pk-fp16 floor), MFMA 20%,
// 35% idle; occupancy capped at 3 blocks/CU by 6 accs (168 unified regs).
// R12 = NI=4: one m-tile, wave w owns n-tile w (both p, in-register combine);
// tile 4 runs as a second short k-loop on wave 0 after its first accs retire
// -> never more than 2 live accumulators (~90 regs) -> 5 blocks/CU.
// Row stride padded to 156 halves: B-frag bank conflicts 4-way -> 2-way(free).
// 0.5 folded into prepped weights (relu positively homogeneous).
// Algorithm (verified R7-R11): Xn=nA@x, Xi=iA@x (cooperative premix);
//   x_new = relu(Xn@(W1/2)) + relu(Xi@(W2/2)) as MFMA epilogue.
// wt layout (d_ws): [l][p][nt][ks][lane][j8], n=nt*32+(lane&31) (>=144 pad0),
//   k=ks*16+(lane>>5)*8+j8. 1 KB per fragment, coalesced.
// MFMA: A[n][k]=Wt, B[k][m]=Xmix -> D[n][m];
// C/D: col=lane&31 (=m), row=(reg&3)+8*(reg>>2)+4*(lane>>5) (=n).
// LDS: sX + sXn + sXi (28x156 fp16) + sAh = 27.1 KB.

typedef _Float16 half8   __attribute__((ext_vector_type(8)));
typedef _Float16 half4_t __attribute__((ext_vector_type(4)));
typedef float    floatx16 __attribute__((ext_vector_type(16)));

constexpr int GS = 7;
constexpr int NI = 4;           // graphs per block
constexpr int MROWS = NI * GS;  // 28
constexpr int H = 144;
constexpr int XS = 156;         // LDS row stride in halves (2-way-free banks)
constexpr int LSTRIDE = 2 * 5 * 9 * 512;  // 46080 halfs per layer
constexpr int WT_HALFS = 3 * LSTRIDE;     // 138240
constexpr int FRAGS = 3 * 90 * 64;        // thread-slices in prep (17280)

static __device__ inline half8 bc(_Float16 v) {
    half8 h = {v, v, v, v, v, v, v, v};
    return h;
}

// ---------------- prologue: weights*0.5 -> fragment-linear fp16, g = fc2 @ fc1 ----------------
__global__ void prep_kernel(const float* __restrict__ w10, const float* __restrict__ w20,
                            const float* __restrict__ w11, const float* __restrict__ w21,
                            const float* __restrict__ w12, const float* __restrict__ w22,
                            const float* __restrict__ fc1, const float* __restrict__ fc2,
                            _Float16* __restrict__ wt, float* __restrict__ g)
{
    if (blockIdx.x == 68) {             // g = fc2 @ fc1 (both linear, no act)
        const int j = threadIdx.x;
        if (j < H) {
            float s = 0.f;
            for (int o = 0; o < 128; ++o) s = fmaf(fc2[o], fc1[o * H + j], s);
            g[j] = s;
        }
        return;
    }
    const int t = blockIdx.x * 256 + threadIdx.x;
    if (t >= FRAGS) return;
    const int l    = t / (90 * 64);
    const int r    = t - l * (90 * 64);
    const int frag = r >> 6;            // 0..89
    const int lane = r & 63;
    const int p    = frag / 45;         // 0 -> W1, 1 -> W2
    const int rem  = frag - p * 45;
    const int nt   = rem / 9;
    const int ks   = rem - nt * 9;
    const int n    = nt * 32 + (lane & 31);           // out-col 0..159
    const int k0   = ks * 16 + (lane >> 5) * 8;       // in-dim base
    const float* W = (l == 0) ? (p ? w20 : w10)
                   : (l == 1) ? (p ? w21 : w11)
                              : (p ? w22 : w12);
    const int K = (l == 0) ? 5 : 144;
    half8 h = bc((_Float16)0);
    #pragma unroll
    for (int j = 0; j < 8; ++j) {
        const int k = k0 + j;
        if (n < H && k < K) h[j] = (_Float16)(0.5f * W[k * H + n]);  // 0.5 folded in
    }
    *(half8*)(wt + (size_t)l * LSTRIDE + (size_t)frag * 512 + (size_t)lane * 8) = h;
}

// ---- one full layer: cooperative premix, wave-owned GEMM, in-register epilogue ----
// Called uniformly by all 256 threads; barriers are workgroup-uniform.
template<int NK, int CB>
static __device__ __forceinline__ void layer_pass(const _Float16* __restrict__ wl,
                                                  const int tid, const int lane, const int wv,
                                                  _Float16 (*sX)[XS],
                                                  _Float16 (*sXn)[XS], _Float16 (*sXi)[XS],
                                                  const _Float16 (*sAh)[2][GS][8])
{
    // ---- cooperative premix: Xn = nA@x, Xi = iA@x ----
    for (int u = tid; u < MROWS * CB; u += 256) {
        const int row = u / CB, cb = u - row * CB;
        const int item = row / GS, rr = row - item * GS;
        const int c0 = cb * 8;
        const half8 aN = *(const half8*)&sAh[item][0][rr][0];
        const half8 aI = *(const half8*)&sAh[item][1][rr][0];
        half8 an = bc((_Float16)0), ai = bc((_Float16)0);
        #pragma unroll
        for (int j = 0; j < GS; ++j) {
            const half8 xj = *(const half8*)&sX[item * GS + j][c0];
            an += bc(aN[j]) * xj;
            ai += bc(aI[j]) * xj;
        }
        *(half8*)&sXn[row][c0] = an;
        *(half8*)&sXi[row][c0] = ai;
    }
    __syncthreads();   // B1: Xn/Xi ready; all reads of old sX complete

    const int khi = (lane >> 5) * 8;
    const int r0  = lane & 31;                        // D col = graph row
    const int rc  = (r0 < MROWS) ? r0 : (MROWS - 1);  // clamped B-frag source

    // ---- main tile nt = wv (both p halves in-register) ----
    {
        floatx16 a1, a2;
        #pragma unroll
        for (int i = 0; i < 16; ++i) { a1[i] = 0.f; a2[i] = 0.f; }
        #pragma unroll
        for (int ks = 0; ks < NK; ++ks) {
            const int c = ks * 16 + khi;
            const half8 bn = *(const half8*)&sXn[rc][c];
            const half8 bi = *(const half8*)&sXi[rc][c];
            const _Float16* f = wl + (size_t)((wv * 9 + ks) * 512) + (size_t)lane * 8;
            a1 = __builtin_amdgcn_mfma_f32_32x32x16_f16(*(const half8*)f,              bn, a1, 0, 0, 0);
            a2 = __builtin_amdgcn_mfma_f32_32x32x16_f16(*(const half8*)(f + 45 * 512), bi, a2, 0, 0, 0);
        }
        if (r0 < MROWS) {
            #pragma unroll
            for (int q = 0; q < 4; ++q) {          // tiles 0..3: cols < 128, all valid
                const int n0 = wv * 32 + 4 * (lane >> 5) + 8 * q;
                half4_t h;
                #pragma unroll
                for (int i = 0; i < 4; ++i) {
                    float v1 = a1[4 * q + i]; v1 = v1 > 0.f ? v1 : 0.f;
                    float v2 = a2[4 * q + i]; v2 = v2 > 0.f ? v2 : 0.f;
                    h[i] = (_Float16)(v1 + v2);    // 0.5 folded into weights
                }
                *(half4_t*)&sX[r0][n0] = h;
            }
        }
    }

    // ---- tile 4 (cols 128..143) on wave 0, after first accs retired ----
    if (wv == 0) {
        floatx16 e1, e2;
        #pragma unroll
        for (int i = 0; i < 16; ++i) { e1[i] = 0.f; e2[i] = 0.f; }
        #pragma unroll
        for (int ks = 0; ks < NK; ++ks) {
            const int c = ks * 16 + khi;
            const half8 bn = *(const half8*)&sXn[rc][c];
            const half8 bi = *(const half8*)&sXi[rc][c];
            const _Float16* f = wl + (size_t)((36 + ks) * 512) + (size_t)lane * 8;
            e1 = __builtin_amdgcn_mfma_f32_32x32x16_f16(*(const half8*)f,              bn, e1, 0, 0, 0);
            e2 = __builtin_amdgcn_mfma_f32_32x32x16_f16(*(const half8*)(f + 45 * 512), bi, e2, 0, 0, 0);
        }
        if (r0 < MROWS) {
            #pragma unroll
            for (int q = 0; q < 2; ++q) {          // cols 128..143 only
                const int n0 = 128 + 4 * (lane >> 5) + 8 * q;
                half4_t h;
                #pragma unroll
                for (int i = 0; i < 4; ++i) {
                    float v1 = e1[4 * q + i]; v1 = v1 > 0.f ? v1 : 0.f;
                    float v2 = e2[4 * q + i]; v2 = v2 > 0.f ? v2 : 0.f;
                    h[i] = (_Float16)(v1 + v2);
                }
                *(half4_t*)&sX[r0][n0] = h;
            }
        }
    }
    __syncthreads();   // B2: x_new visible for next premix / pool
}

__global__ __launch_bounds__(256, 5)
void gcn_mfma(const float* __restrict__ ops, const float* __restrict__ adj,
              const float* __restrict__ nv,
              const _Float16* __restrict__ wt, const float* __restrict__ gw,
              float* __restrict__ out)
{
    __shared__ __align__(16) _Float16 sX [MROWS][XS];    // 8736 B
    __shared__ __align__(16) _Float16 sXn[MROWS][XS];    // 8736 B
    __shared__ __align__(16) _Float16 sXi[MROWS][XS];    // 8736 B
    __shared__ __align__(16) _Float16 sAh[NI][2][GS][8]; //  896 B  total 27104 B

    float (*adjd)[GS][GS] = (float(*)[GS][GS])&sXn[0][0];   // prologue-only scratch

    const int tid  = threadIdx.x;
    const int lane = tid & 63;
    const int wv   = tid >> 6;
    const int ibase = blockIdx.x * NI;

    // ---------------- per-block prologue: stage X (fp16), adjacency matrices ----------------
    if (tid < MROWS) {
        const int item = tid / GS, r = tid % GS;
        const float* orow = ops + ((size_t)(ibase + item) * GS + r) * 5;
        half8 h = bc((_Float16)0);
        h[0] = (_Float16)orow[0]; h[1] = (_Float16)orow[1]; h[2] = (_Float16)orow[2];
        h[3] = (_Float16)orow[3]; h[4] = (_Float16)orow[4];
        *(half8*)&sX[tid][0] = h;
        *(half8*)&sX[tid][8] = bc((_Float16)0);   // layer-0 K pad (k=5..15)

        const float* arow = adj + ((size_t)(ibase + item) * GS + r) * GS;
        float a[GS]; float sm = 0.f;
        #pragma unroll
        for (int c = 0; c < GS; ++c) { a[c] = arow[c] + (c == r ? 1.f : 0.f); sm += a[c]; }
        const float is = 1.f / sm;
        #pragma unroll
        for (int c = 0; c < GS; ++c) {
            const float v = a[c] * is;
            adjd[item][r][c] = v;
            sAh[item][0][r][c] = (_Float16)v;
        }
        sAh[item][0][r][7] = (_Float16)0.f;
    }
    __syncthreads();
    if (tid < MROWS) {    // inv_norm_adj = row_normalize(adj_d^T)
        const int item = tid / GS, r = tid % GS;
        float v[GS]; float sm = 0.f;
        #pragma unroll
        for (int k = 0; k < GS; ++k) { v[k] = adjd[item][k][r]; sm += v[k]; }
        const float is = 1.f / sm;
        #pragma unroll
        for (int k = 0; k < GS; ++k) sAh[item][1][r][k] = (_Float16)(v[k] * is);
        sAh[item][1][r][7] = (_Float16)0.f;
    }
    __syncthreads();

    // ==================== 3 layers ====================
    layer_pass<1, 2>(wt,                        tid, lane, wv, sX, sXn, sXi, sAh);
    layer_pass<9, 18>(wt + (size_t)1 * LSTRIDE, tid, lane, wv, sX, sXn, sXi, sAh);
    layer_pass<9, 18>(wt + (size_t)2 * LSTRIDE, tid, lane, wv, sX, sXn, sXi, sAh);

    // ==================== pool + (fc2@fc1) dot ====================
    if (tid < NI * 16) {
        const int item = tid >> 4, part = tid & 15;
        float s = 0.f;
        #pragma unroll
        for (int c = 0; c < 9; ++c) {
            const int j = part * 9 + c;
            const float gj = gw[j];
            #pragma unroll
            for (int i = 0; i < GS; ++i)
                s = fmaf((float)sX[item * GS + i][j], gj, s);
        }
        s += __shfl_xor(s, 1);
        s += __shfl_xor(s, 2);
        s += __shfl_xor(s, 4);
        s += __shfl_xor(s, 8);
        if (part == 0) out[ibase + item] = s / nv[ibase + item];
    }
}

extern "C" void kernel_launch(void* const* d_in, const int* in_sizes, int n_in,
                              void* d_out, int out_size, void* d_ws, size_t ws_size,
                              hipStream_t stream) {
    const float* ops = (const float*)d_in[0];
    const float* adj = (const float*)d_in[1];
    const float* nv  = (const float*)d_in[2];
    const float* w10 = (const float*)d_in[3];
    const float* w20 = (const float*)d_in[4];
    const float* w11 = (const float*)d_in[5];
    const float* w21 = (const float*)d_in[6];
    const float* w12 = (const float*)d_in[7];
    const float* w22 = (const float*)d_in[8];
    const float* fc1 = (const float*)d_in[9];
    const float* fc2 = (const float*)d_in[10];

    _Float16* wt = (_Float16*)d_ws;                              // 276480 B
    float*    g  = (float*)((char*)d_ws + (size_t)WT_HALFS * 2); // 576 B

    prep_kernel<<<69, 256, 0, stream>>>(w10, w20, w11, w21, w12, w22,
                                        fc1, fc2, wt, g);
    gcn_mfma<<<65536 / NI, 256, 0, stream>>>(ops, adj, nv, wt, g, (float*)d_out);
}

// Round 13
// 562.042 us; speedup vs baseline: 1.0282x; 1.0282x over previous
//
#include <hip/hip_runtime.h>

// Fused 3-layer GCN (GS=7, H=144) + pool + fc, B=65536.  Round 13.
// R12's NI=4 structure was right (bank conflicts -83%, occupancy 53%) but
// __launch_bounds__(256,5) capped regs at ~102/wave < the ~130 needed ->
// accumulators spilled to scratch (760 MB HBM traffic/dispatch, VGPR 48).
// R13 = R12 with __launch_bounds__(256,4): cap 128 regs, no spill,
// 4 blocks/CU (LDS 27.1 KB x4 = 108 KB).
// Algorithm (verified R7-R12): Xn=nA@x, Xi=iA@x (cooperative premix);
//   x_new = relu(Xn@(W1/2)) + relu(Xi@(W2/2)) as MFMA epilogue (0.5 folded).
// wt layout (d_ws): [l][p][nt][ks][lane][j8], n=nt*32+(lane&31) (>=144 pad0),
//   k=ks*16+(lane>>5)*8+j8. 1 KB per fragment, coalesced.
// MFMA: A[n][k]=Wt, B[k][m]=Xmix -> D[n][m];
// C/D: col=lane&31 (=m), row=(reg&3)+8*(reg>>2)+4*(lane>>5) (=n).
// LDS: sX + sXn + sXi (28x156 fp16, 2-way-free banks) + sAh = 27.1 KB.

typedef _Float16 half8   __attribute__((ext_vector_type(8)));
typedef _Float16 half4_t __attribute__((ext_vector_type(4)));
typedef float    floatx16 __attribute__((ext_vector_type(16)));

constexpr int GS = 7;
constexpr int NI = 4;           // graphs per block
constexpr int MROWS = NI * GS;  // 28
constexpr int H = 144;
constexpr int XS = 156;         // LDS row stride in halves (2-way-free banks)
constexpr int LSTRIDE = 2 * 5 * 9 * 512;  // 46080 halfs per layer
constexpr int WT_HALFS = 3 * LSTRIDE;     // 138240
constexpr int FRAGS = 3 * 90 * 64;        // thread-slices in prep (17280)

static __device__ inline half8 bc(_Float16 v) {
    half8 h = {v, v, v, v, v, v, v, v};
    return h;
}

// ---------------- prologue: weights*0.5 -> fragment-linear fp16, g = fc2 @ fc1 ----------------
__global__ void prep_kernel(const float* __restrict__ w10, const float* __restrict__ w20,
                            const float* __restrict__ w11, const float* __restrict__ w21,
                            const float* __restrict__ w12, const float* __restrict__ w22,
                            const float* __restrict__ fc1, const float* __restrict__ fc2,
                            _Float16* __restrict__ wt, float* __restrict__ g)
{
    if (blockIdx.x == 68) {             // g = fc2 @ fc1 (both linear, no act)
        const int j = threadIdx.x;
        if (j < H) {
            float s = 0.f;
            for (int o = 0; o < 128; ++o) s = fmaf(fc2[o], fc1[o * H + j], s);
            g[j] = s;
        }
        return;
    }
    const int t = blockIdx.x * 256 + threadIdx.x;
    if (t >= FRAGS) return;
    const int l    = t / (90 * 64);
    const int r    = t - l * (90 * 64);
    const int frag = r >> 6;            // 0..89
    const int lane = r & 63;
    const int p    = frag / 45;         // 0 -> W1, 1 -> W2
    const int rem  = frag - p * 45;
    const int nt   = rem / 9;
    const int ks   = rem - nt * 9;
    const int n    = nt * 32 + (lane & 31);           // out-col 0..159
    const int k0   = ks * 16 + (lane >> 5) * 8;       // in-dim base
    const float* W = (l == 0) ? (p ? w20 : w10)
                   : (l == 1) ? (p ? w21 : w11)
                              : (p ? w22 : w12);
    const int K = (l == 0) ? 5 : 144;
    half8 h = bc((_Float16)0);
    #pragma unroll
    for (int j = 0; j < 8; ++j) {
        const int k = k0 + j;
        if (n < H && k < K) h[j] = (_Float16)(0.5f * W[k * H + n]);  // 0.5 folded in
    }
    *(half8*)(wt + (size_t)l * LSTRIDE + (size_t)frag * 512 + (size_t)lane * 8) = h;
}

// ---- one full layer: cooperative premix, wave-owned GEMM, in-register epilogue ----
// Called uniformly by all 256 threads; barriers are workgroup-uniform.
template<int NK, int CB>
static __device__ __forceinline__ void layer_pass(const _Float16* __restrict__ wl,
                                                  const int tid, const int lane, const int wv,
                                                  _Float16 (*sX)[XS],
                                                  _Float16 (*sXn)[XS], _Float16 (*sXi)[XS],
                                                  const _Float16 (*sAh)[2][GS][8])
{
    // ---- cooperative premix: Xn = nA@x, Xi = iA@x ----
    for (int u = tid; u < MROWS * CB; u += 256) {
        const int row = u / CB, cb = u - row * CB;
        const int item = row / GS, rr = row - item * GS;
        const int c0 = cb * 8;
        const half8 aN = *(const half8*)&sAh[item][0][rr][0];
        const half8 aI = *(const half8*)&sAh[item][1][rr][0];
        half8 an = bc((_Float16)0), ai = bc((_Float16)0);
        #pragma unroll
        for (int j = 0; j < GS; ++j) {
            const half8 xj = *(const half8*)&sX[item * GS + j][c0];
            an += bc(aN[j]) * xj;
            ai += bc(aI[j]) * xj;
        }
        *(half8*)&sXn[row][c0] = an;
        *(half8*)&sXi[row][c0] = ai;
    }
    __syncthreads();   // B1: Xn/Xi ready; all reads of old sX complete

    const int khi = (lane >> 5) * 8;
    const int r0  = lane & 31;                        // D col = graph row
    const int rc  = (r0 < MROWS) ? r0 : (MROWS - 1);  // clamped B-frag source

    // ---- main tile nt = wv (both p halves in-register) ----
    {
        floatx16 a1, a2;
        #pragma unroll
        for (int i = 0; i < 16; ++i) { a1[i] = 0.f; a2[i] = 0.f; }
        #pragma unroll
        for (int ks = 0; ks < NK; ++ks) {
            const int c = ks * 16 + khi;
            const half8 bn = *(const half8*)&sXn[rc][c];
            const half8 bi = *(const half8*)&sXi[rc][c];
            const _Float16* f = wl + (size_t)((wv * 9 + ks) * 512) + (size_t)lane * 8;
            a1 = __builtin_amdgcn_mfma_f32_32x32x16_f16(*(const half8*)f,              bn, a1, 0, 0, 0);
            a2 = __builtin_amdgcn_mfma_f32_32x32x16_f16(*(const half8*)(f + 45 * 512), bi, a2, 0, 0, 0);
        }
        if (r0 < MROWS) {
            #pragma unroll
            for (int q = 0; q < 4; ++q) {          // tiles 0..3: cols < 128, all valid
                const int n0 = wv * 32 + 4 * (lane >> 5) + 8 * q;
                half4_t h;
                #pragma unroll
                for (int i = 0; i < 4; ++i) {
                    float v1 = a1[4 * q + i]; v1 = v1 > 0.f ? v1 : 0.f;
                    float v2 = a2[4 * q + i]; v2 = v2 > 0.f ? v2 : 0.f;
                    h[i] = (_Float16)(v1 + v2);    // 0.5 folded into weights
                }
                *(half4_t*)&sX[r0][n0] = h;
            }
        }
    }

    // ---- tile 4 (cols 128..143) on wave 0, after first accs retired ----
    if (wv == 0) {
        floatx16 e1, e2;
        #pragma unroll
        for (int i = 0; i < 16; ++i) { e1[i] = 0.f; e2[i] = 0.f; }
        #pragma unroll
        for (int ks = 0; ks < NK; ++ks) {
            const int c = ks * 16 + khi;
            const half8 bn = *(const half8*)&sXn[rc][c];
            const half8 bi = *(const half8*)&sXi[rc][c];
            const _Float16* f = wl + (size_t)((36 + ks) * 512) + (size_t)lane * 8;
            e1 = __builtin_amdgcn_mfma_f32_32x32x16_f16(*(const half8*)f,              bn, e1, 0, 0, 0);
            e2 = __builtin_amdgcn_mfma_f32_32x32x16_f16(*(const half8*)(f + 45 * 512), bi, e2, 0, 0, 0);
        }
        if (r0 < MROWS) {
            #pragma unroll
            for (int q = 0; q < 2; ++q) {          // cols 128..143 only
                const int n0 = 128 + 4 * (lane >> 5) + 8 * q;
                half4_t h;
                #pragma unroll
                for (int i = 0; i < 4; ++i) {
                    float v1 = e1[4 * q + i]; v1 = v1 > 0.f ? v1 : 0.f;
                    float v2 = e2[4 * q + i]; v2 = v2 > 0.f ? v2 : 0.f;
                    h[i] = (_Float16)(v1 + v2);
                }
                *(half4_t*)&sX[r0][n0] = h;
            }
        }
    }
    __syncthreads();   // B2: x_new visible for next premix / pool
}

__global__ __launch_bounds__(256, 4)
void gcn_mfma(const float* __restrict__ ops, const float* __restrict__ adj,
              const float* __restrict__ nv,
              const _Float16* __restrict__ wt, const float* __restrict__ gw,
              float* __restrict__ out)
{
    __shared__ __align__(16) _Float16 sX [MROWS][XS];    // 8736 B
    __shared__ __align__(16) _Float16 sXn[MROWS][XS];    // 8736 B
    __shared__ __align__(16) _Float16 sXi[MROWS][XS];    // 8736 B
    __shared__ __align__(16) _Float16 sAh[NI][2][GS][8]; //  896 B  total 27104 B

    float (*adjd)[GS][GS] = (float(*)[GS][GS])&sXn[0][0];   // prologue-only scratch

    const int tid  = threadIdx.x;
    const int lane = tid & 63;
    const int wv   = tid >> 6;
    const int ibase = blockIdx.x * NI;

    // ---------------- per-block prologue: stage X (fp16), adjacency matrices ----------------
    if (tid < MROWS) {
        const int item = tid / GS, r = tid % GS;
        const float* orow = ops + ((size_t)(ibase + item) * GS + r) * 5;
        half8 h = bc((_Float16)0);
        h[0] = (_Float16)orow[0]; h[1] = (_Float16)orow[1]; h[2] = (_Float16)orow[2];
        h[3] = (_Float16)orow[3]; h[4] = (_Float16)orow[4];
        *(half8*)&sX[tid][0] = h;
        *(half8*)&sX[tid][8] = bc((_Float16)0);   // layer-0 K pad (k=5..15)

        const float* arow = adj + ((size_t)(ibase + item) * GS + r) * GS;
        float a[GS]; float sm = 0.f;
        #pragma unroll
        for (int c = 0; c < GS; ++c) { a[c] = arow[c] + (c == r ? 1.f : 0.f); sm += a[c]; }
        const float is = 1.f / sm;
        #pragma unroll
        for (int c = 0; c < GS; ++c) {
            const float v = a[c] * is;
            adjd[item][r][c] = v;
            sAh[item][0][r][c] = (_Float16)v;
        }
        sAh[item][0][r][7] = (_Float16)0.f;
    }
    __syncthreads();
    if (tid < MROWS) {    // inv_norm_adj = row_normalize(adj_d^T)
        const int item = tid / GS, r = tid % GS;
        float v[GS]; float sm = 0.f;
        #pragma unroll
        for (int k = 0; k < GS; ++k) { v[k] = adjd[item][k][r]; sm += v[k]; }
        const float is = 1.f / sm;
        #pragma unroll
        for (int k = 0; k < GS; ++k) sAh[item][1][r][k] = (_Float16)(v[k] * is);
        sAh[item][1][r][7] = (_Float16)0.f;
    }
    __syncthreads();

    // ==================== 3 layers ====================
    layer_pass<1, 2>(wt,                        tid, lane, wv, sX, sXn, sXi, sAh);
    layer_pass<9, 18>(wt + (size_t)1 * LSTRIDE, tid, lane, wv, sX, sXn, sXi, sAh);
    layer_pass<9, 18>(wt + (size_t)2 * LSTRIDE, tid, lane, wv, sX, sXn, sXi, sAh);

    // ==================== pool + (fc2@fc1) dot ====================
    if (tid < NI * 16) {
        const int item = tid >> 4, part = tid & 15;
        float s = 0.f;
        #pragma unroll
        for (int c = 0; c < 9; ++c) {
            const int j = part * 9 + c;
            const float gj = gw[j];
            #pragma unroll
            for (int i = 0; i < GS; ++i)
                s = fmaf((float)sX[item * GS + i][j], gj, s);
        }
        s += __shfl_xor(s, 1);
        s += __shfl_xor(s, 2);
        s += __shfl_xor(s, 4);
        s += __shfl_xor(s, 8);
        if (part == 0) out[ibase + item] = s / nv[ibase + item];
    }
}

extern "C" void kernel_launch(void* const* d_in, const int* in_sizes, int n_in,
                              void* d_out, int out_size, void* d_ws, size_t ws_size,
                              hipStream_t stream) {
    const float* ops = (const float*)d_in[0];
    const float* adj = (const float*)d_in[1];
    const float* nv  = (const float*)d_in[2];
    const float* w10 = (const float*)d_in[3];
    const float* w20 = (const float*)d_in[4];
    const float* w11 = (const float*)d_in[5];
    const float* w21 = (const float*)d_in[6];
    const float* w12 = (const float*)d_in[7];
    const float* w22 = (const float*)d_in[8];
    const float* fc1 = (const float*)d_in[9];
    const float* fc2 = (const float*)d_in[10];

    _Float16* wt = (_Float16*)d_ws;                              // 276480 B
    float*    g  = (float*)((char*)d_ws + (size_t)WT_HALFS * 2); // 576 B

    prep_kernel<<<69, 256, 0, stream>>>(w10, w20, w11, w21, w12, w22,
                                        fc1, fc2, wt, g);
    gcn_mfma<<<65536 / NI, 256, 0, stream>>>(ops, adj, nv, wt, g, (float*)d_out);
}